// Round 4
// baseline (464.958 us; speedup 1.0000x reference)
//
#include <hip/hip_runtime.h>
#include <math.h>

#define N_NODES 100000
#define N_EDGES 1600000
#define F 16

#define BSH 6
#define NPB 64                                  // nodes per bucket
#define NB ((N_NODES + NPB - 1) / NPB)          // 1563 buckets
#define NCHUNK 256                              // phase-1 chunk blocks
#define M_COUNTS (NB * NCHUNK)                  // 400128
#define SCAN_B 512
#define NSCAN ((M_COUNTS + SCAN_B - 1) / SCAN_B)  // 782

// ---------------------------------------------------------------------------
// Phase 1a: per-chunk histogram of dst buckets (LDS atomics only).
__global__ __launch_bounds__(1024)
void bucket_hist(const int* __restrict__ dst, int* __restrict__ counts) {
    __shared__ int h[NB];
    int tid = threadIdx.x;
    for (int i = tid; i < NB; i += 1024) h[i] = 0;
    __syncthreads();
    for (int e = blockIdx.x * 1024 + tid; e < N_EDGES; e += NCHUNK * 1024)
        atomicAdd(&h[dst[e] >> BSH], 1);
    __syncthreads();
    for (int i = tid; i < NB; i += 1024)
        counts[i * NCHUNK + blockIdx.x] = h[i];
}

// ---------------------------------------------------------------------------
// Scan of counts (bucket-major) -> exclusive offsets. 3 small kernels.
__global__ __launch_bounds__(SCAN_B)
void blocksum_kernel(const int* __restrict__ a, int n, int* __restrict__ bsum) {
    __shared__ int s[SCAN_B];
    int t = threadIdx.x;
    int i = blockIdx.x * SCAN_B + t;
    s[t] = (i < n) ? a[i] : 0;
    __syncthreads();
    for (int off = SCAN_B / 2; off > 0; off >>= 1) {
        if (t < off) s[t] += s[t + off];
        __syncthreads();
    }
    if (t == 0) bsum[blockIdx.x] = s[0];
}

__global__ __launch_bounds__(1024)
void scan_bsum_kernel(int* __restrict__ bsum, int nb) {
    __shared__ int s[1024];
    int t = threadIdx.x;
    int v = (t < nb) ? bsum[t] : 0;
    s[t] = v;
    __syncthreads();
    for (int off = 1; off < 1024; off <<= 1) {
        int x = (t >= off) ? s[t - off] : 0;
        __syncthreads();
        s[t] += x;
        __syncthreads();
    }
    if (t < nb) bsum[t] = s[t] - v;  // exclusive
}

__global__ __launch_bounds__(SCAN_B)
void scan_write_kernel(const int* __restrict__ a, int n,
                       const int* __restrict__ bsum, int* __restrict__ out) {
    __shared__ int s[SCAN_B];
    int t = threadIdx.x;
    int i = blockIdx.x * SCAN_B + t;
    int v = (i < n) ? a[i] : 0;
    s[t] = v;
    __syncthreads();
    for (int off = 1; off < SCAN_B; off <<= 1) {
        int x = (t >= off) ? s[t - off] : 0;
        __syncthreads();
        s[t] += x;
        __syncthreads();
    }
    if (i < n) out[i] = bsum[blockIdx.x] + s[t] - v;  // exclusive
}

// ---------------------------------------------------------------------------
// Phase 1b: scatter packed records into bucket-grouped layout.
// Slot positions precomputed -> LDS cursor atomics only, zero global atomics.
__global__ __launch_bounds__(1024)
void bucket_scatter(const int* __restrict__ src, const int* __restrict__ dst,
                    const float* __restrict__ u, const int* __restrict__ offsets,
                    int2* __restrict__ rec) {
    __shared__ int cur[NB];
    int tid = threadIdx.x;
    for (int i = tid; i < NB; i += 1024)
        cur[i] = offsets[i * NCHUNK + blockIdx.x];
    __syncthreads();
    for (int e = blockIdx.x * 1024 + tid; e < N_EDGES; e += NCHUNK * 1024) {
        int d = dst[e];
        int b = d >> BSH;
        int pos = atomicAdd(&cur[b], 1);
        rec[pos] = make_int2(src[e] | ((d & (NPB - 1)) << 20),
                             __float_as_int(u[e]));
    }
}

// ---------------------------------------------------------------------------
// Per-node transform: YP2[n*16+o] = {(X@W0)[n,o], (X@(W1-W0))[n,o]}
//                     R[n*16+o]   = (X@root)[n,o] + bias[o]
__global__ void node_transform(const float* __restrict__ X, int fin,
                               const float* __restrict__ W,
                               const float* __restrict__ root,
                               const float* __restrict__ bias,
                               float2* __restrict__ YP2,
                               float* __restrict__ R,
                               int n_nodes) {
    __shared__ float sW0[48 * 16];
    __shared__ float sWd[48 * 16];
    __shared__ float sR[48 * 16];
    __shared__ float sB[16];
    int t = threadIdx.x;
    for (int i = t; i < fin * 16; i += blockDim.x) {
        float w0 = W[i];
        float w1 = W[fin * 16 + i];
        sW0[i] = w0;
        sWd[i] = w1 - w0;
        sR[i]  = root[i];
    }
    if (t < 16) sB[t] = bias[t];
    __syncthreads();

    int idx = blockIdx.x * blockDim.x + t;
    int n = idx >> 4;
    int o = idx & 15;
    if (n >= n_nodes) return;

    const float* xr = X + (long)n * fin;
    float a0 = 0.0f, a1 = 0.0f, ar = 0.0f;
    for (int f = 0; f < fin; ++f) {
        float xv = xr[f];
        a0 = fmaf(xv, sW0[f * 16 + o], a0);
        a1 = fmaf(xv, sWd[f * 16 + o], a1);
        ar = fmaf(xv, sR[f * 16 + o], ar);
    }
    YP2[idx] = make_float2(a0, a1);
    R[idx]   = ar + sB[o];
}

// ---------------------------------------------------------------------------
// Phase 2: per-bucket aggregation in LDS. 16 lanes per edge, stride-17 padded
// accumulator (conflict-free), coalesced record stream, fused epilogue.
__device__ __forceinline__ void bucket_accumulate(
        int beg, int end, int o, int g,
        const int2* __restrict__ rec, const float2* __restrict__ YP2,
        float* __restrict__ acc, int* __restrict__ cnt) {
    int j = beg + g;
    for (; j + 16 < end; j += 32) {
        int2 r0 = rec[j];
        int2 r1 = rec[j + 16];
        float2 y0 = YP2[(r0.x & 0xFFFFF) * 16 + o];
        float2 y1 = YP2[(r1.x & 0xFFFFF) * 16 + o];
        int d0 = r0.x >> 20;
        int d1 = r1.x >> 20;
        atomicAdd(&acc[d0 * 17 + o], fmaf(__int_as_float(r0.y), y0.y, y0.x));
        atomicAdd(&acc[d1 * 17 + o], fmaf(__int_as_float(r1.y), y1.y, y1.x));
        if (o == 0) { atomicAdd(&cnt[d0], 1); atomicAdd(&cnt[d1], 1); }
    }
    if (j < end) {
        int2 r0 = rec[j];
        float2 y0 = YP2[(r0.x & 0xFFFFF) * 16 + o];
        int d0 = r0.x >> 20;
        atomicAdd(&acc[d0 * 17 + o], fmaf(__int_as_float(r0.y), y0.y, y0.x));
        if (o == 0) atomicAdd(&cnt[d0], 1);
    }
}

__global__ __launch_bounds__(256)
void aggregate_elu(const int* __restrict__ offsets, const int2* __restrict__ rec,
                   const float2* __restrict__ YP2, const float* __restrict__ R,
                   float* __restrict__ H) {
    __shared__ float acc[NPB * 17];
    __shared__ int cnt[NPB];
    int tid = threadIdx.x;
    for (int i = tid; i < NPB * 17; i += 256) acc[i] = 0.0f;
    if (tid < NPB) cnt[tid] = 0;
    __syncthreads();
    int b = blockIdx.x;
    int beg = offsets[b * NCHUNK];
    int end = (b + 1 < NB) ? offsets[(b + 1) * NCHUNK] : N_EDGES;
    bucket_accumulate(beg, end, tid & 15, tid >> 4, rec, YP2, acc, cnt);
    __syncthreads();

    int node0 = b << BSH;
    int nvalid = N_NODES - node0;
    if (nvalid > NPB) nvalid = NPB;
    for (int i = tid; i < nvalid * 16; i += 256) {
        int n = i >> 4, of = i & 15;
        int gn = node0 + n;
        float c = (float)(cnt[n] > 0 ? cnt[n] : 1);
        float v = acc[n * 17 + of] / c + R[gn * 16 + of];
        H[gn * 16 + of] = v > 0.0f ? v : expm1f(v);
    }
}

__global__ __launch_bounds__(256)
void aggregate_logsoftmax(const int* __restrict__ offsets,
                          const int2* __restrict__ rec,
                          const float2* __restrict__ YP2,
                          const float* __restrict__ R,
                          float* __restrict__ out) {
    __shared__ float acc[NPB * 17];
    __shared__ int cnt[NPB];
    int tid = threadIdx.x;
    for (int i = tid; i < NPB * 17; i += 256) acc[i] = 0.0f;
    if (tid < NPB) cnt[tid] = 0;
    __syncthreads();
    int b = blockIdx.x;
    int beg = offsets[b * NCHUNK];
    int end = (b + 1 < NB) ? offsets[(b + 1) * NCHUNK] : N_EDGES;
    bucket_accumulate(beg, end, tid & 15, tid >> 4, rec, YP2, acc, cnt);
    __syncthreads();

    int node0 = b << BSH;
    int nvalid = N_NODES - node0;
    if (nvalid > NPB) nvalid = NPB;
    if (tid < nvalid) {
        int gn = node0 + tid;
        float inv = 1.0f / (float)(cnt[tid] > 0 ? cnt[tid] : 1);
        float v[16];
        const float4* rp = (const float4*)(R + (long)gn * 16);
        float m = -INFINITY;
#pragma unroll
        for (int q = 0; q < 4; ++q) {
            float4 rr = rp[q];
            v[4 * q + 0] = fmaf(acc[tid * 17 + 4 * q + 0], inv, rr.x);
            v[4 * q + 1] = fmaf(acc[tid * 17 + 4 * q + 1], inv, rr.y);
            v[4 * q + 2] = fmaf(acc[tid * 17 + 4 * q + 2], inv, rr.z);
            v[4 * q + 3] = fmaf(acc[tid * 17 + 4 * q + 3], inv, rr.w);
        }
#pragma unroll
        for (int i = 0; i < 16; ++i) m = fmaxf(m, v[i]);
        float s = 0.0f;
#pragma unroll
        for (int i = 0; i < 16; ++i) s += expf(v[i] - m);
        float lse = m + logf(s);
        float4* op = (float4*)(out + (long)gn * 16);
#pragma unroll
        for (int q = 0; q < 4; ++q) {
            float4 o;
            o.x = v[4 * q + 0] - lse;
            o.y = v[4 * q + 1] - lse;
            o.z = v[4 * q + 2] - lse;
            o.w = v[4 * q + 3] - lse;
            op[q] = o;
        }
    }
}

// ---------------------------------------------------------------------------
extern "C" void kernel_launch(void* const* d_in, const int* in_sizes, int n_in,
                              void* d_out, int out_size, void* d_ws, size_t ws_size,
                              hipStream_t stream) {
    const float* x         = (const float*)d_in[0];
    const float* edge_attr = (const float*)d_in[1];
    const int*   edge_idx  = (const int*)d_in[2];
    const float* W1        = (const float*)d_in[3];
    const float* root1     = (const float*)d_in[4];
    const float* b1        = (const float*)d_in[5];
    const float* W2        = (const float*)d_in[6];
    const float* root2     = (const float*)d_in[7];
    const float* b2        = (const float*)d_in[8];
    float* out = (float*)d_out;

    const int* src = edge_idx;
    const int* dst = edge_idx + N_EDGES;

    // workspace layout (16B-aligned base)
    char* ws = (char*)d_ws;
    int2*   rec     = (int2*)ws;                                  // 12.8 MB
    float2* YP2     = (float2*)(ws + (size_t)N_EDGES * 8);        // 12.8 MB
    float*  R       = (float*)((char*)YP2 + (size_t)N_NODES * 16 * 8);  // 6.4 MB
    float*  H       = R + (size_t)N_NODES * 16;                   // 6.4 MB
    int*    counts  = (int*)(H + (size_t)N_NODES * 16);           // 1.6 MB
    int*    offsets = counts + M_COUNTS;                          // 1.6 MB
    int*    bsum    = offsets + M_COUNTS;                         // 782 ints

    dim3 gNF((N_NODES * F + 255) / 256);

    // ---- build bucketed edge records (zero global atomics) ----
    bucket_hist<<<NCHUNK, 1024, 0, stream>>>(dst, counts);
    blocksum_kernel<<<NSCAN, SCAN_B, 0, stream>>>(counts, M_COUNTS, bsum);
    scan_bsum_kernel<<<1, 1024, 0, stream>>>(bsum, NSCAN);
    scan_write_kernel<<<NSCAN, SCAN_B, 0, stream>>>(counts, M_COUNTS, bsum, offsets);
    bucket_scatter<<<NCHUNK, 1024, 0, stream>>>(src, dst, edge_attr, offsets, rec);

    // ---- layer 1 ----
    node_transform<<<gNF, 256, 0, stream>>>(x, 48, W1, root1, b1, YP2, R, N_NODES);
    aggregate_elu<<<NB, 256, 0, stream>>>(offsets, rec, YP2, R, H);

    // ---- layer 2 ----
    node_transform<<<gNF, 256, 0, stream>>>(H, 16, W2, root2, b2, YP2, R, N_NODES);
    aggregate_logsoftmax<<<NB, 256, 0, stream>>>(offsets, rec, YP2, R, out);
}

// Round 5
// 288.684 us; speedup vs baseline: 1.6106x; 1.6106x over previous
//
#include <hip/hip_runtime.h>
#include <math.h>

#define N_NODES 100000
#define N_EDGES 1600000
#define F 16

// ---------------------------------------------------------------------------
// bf16 round-to-nearest-even (no NaN handling needed here)
__device__ __forceinline__ unsigned bf16_rne(float x) {
    unsigned u = __float_as_uint(x);
    return (u + 0x7FFFu + ((u >> 16) & 1u)) >> 16;
}

// ---------------------------------------------------------------------------
// One pass: rec[e] = {next, src | u15<<17}; head[dst] = e.
// 8B coalesced record writes; one 4B atomicExch per edge.
__global__ void build_links(const int* __restrict__ src,
                            const int* __restrict__ dst,
                            const float* __restrict__ u,
                            int* __restrict__ head,
                            int2* __restrict__ rec) {
    int e = blockIdx.x * blockDim.x + threadIdx.x;
    if (e >= N_EDGES) return;
    int d = dst[e];
    int nx = atomicExch(&head[d], e);
    float uu = u[e];
    uu = uu < 0.0f ? 0.0f : (uu > 1.0f ? 1.0f : uu);
    int u15 = (int)fmaf(uu, 32767.0f, 0.5f);
    rec[e] = make_int2(nx, src[e] | (u15 << 17));
}

// ---------------------------------------------------------------------------
// Per-node transform:
//   YPH[n*16+o] = bf16(X@W0)[n,o] | bf16(X@(W1-W0))[n,o] << 16   (64 B/node)
//   R[n*16+o]   = (X@root)[n,o] + bias[o]                        (fp32)
__global__ void node_transform(const float* __restrict__ X, int fin,
                               const float* __restrict__ W,
                               const float* __restrict__ root,
                               const float* __restrict__ bias,
                               unsigned* __restrict__ YPH,
                               float* __restrict__ R,
                               int n_nodes) {
    __shared__ float sW0[48 * 16];
    __shared__ float sWd[48 * 16];
    __shared__ float sR[48 * 16];
    __shared__ float sB[16];
    int t = threadIdx.x;
    for (int i = t; i < fin * 16; i += blockDim.x) {
        float w0 = W[i];
        float w1 = W[fin * 16 + i];
        sW0[i] = w0;
        sWd[i] = w1 - w0;
        sR[i]  = root[i];
    }
    if (t < 16) sB[t] = bias[t];
    __syncthreads();

    int idx = blockIdx.x * blockDim.x + t;
    int n = idx >> 4;
    int o = idx & 15;
    if (n >= n_nodes) return;

    const float* xr = X + (long)n * fin;
    float a0 = 0.0f, a1 = 0.0f, ar = 0.0f;
    for (int f = 0; f < fin; ++f) {
        float xv = xr[f];
        a0 = fmaf(xv, sW0[f * 16 + o], a0);
        a1 = fmaf(xv, sWd[f * 16 + o], a1);
        ar = fmaf(xv, sR[f * 16 + o], ar);
    }
    YPH[idx] = bf16_rne(a0) | (bf16_rne(a1) << 16);
    R[idx]   = ar + sB[o];
}

// ---------------------------------------------------------------------------
// One chain (node) per lane; 16 features in registers.
// Per hop: 8 B rec + 64 B YPH gather.
__device__ __forceinline__ void chain_accumulate(int n,
                                                 const int* __restrict__ head,
                                                 const int2* __restrict__ rec,
                                                 const uint4* __restrict__ YPH,
                                                 float acc[16], float* inv_deg) {
#pragma unroll
    for (int i = 0; i < 16; ++i) acc[i] = 0.0f;
    int e = head[n];
    int deg = 0;
    while (e >= 0) {
        int2 r = rec[e];
        unsigned pk = (unsigned)r.y;
        float uu = (float)(pk >> 17) * (1.0f / 32767.0f);
        const uint4* yp = YPH + (size_t)(pk & 0x1FFFFu) * 4;
#pragma unroll
        for (int q = 0; q < 4; ++q) {
            uint4 w = yp[q];
            float y0, y1;
            y0 = __uint_as_float(w.x << 16);
            y1 = __uint_as_float(w.x & 0xFFFF0000u);
            acc[4 * q + 0] += fmaf(uu, y1, y0);
            y0 = __uint_as_float(w.y << 16);
            y1 = __uint_as_float(w.y & 0xFFFF0000u);
            acc[4 * q + 1] += fmaf(uu, y1, y0);
            y0 = __uint_as_float(w.z << 16);
            y1 = __uint_as_float(w.z & 0xFFFF0000u);
            acc[4 * q + 2] += fmaf(uu, y1, y0);
            y0 = __uint_as_float(w.w << 16);
            y1 = __uint_as_float(w.w & 0xFFFF0000u);
            acc[4 * q + 3] += fmaf(uu, y1, y0);
        }
        ++deg;
        e = r.x;
    }
    *inv_deg = 1.0f / (deg > 0 ? (float)deg : 1.0f);
}

__global__ void aggregate_elu(const int* __restrict__ head,
                              const int2* __restrict__ rec,
                              const uint4* __restrict__ YPH,
                              const float* __restrict__ R,
                              float* __restrict__ H) {
    int n = blockIdx.x * blockDim.x + threadIdx.x;
    if (n >= N_NODES) return;
    float acc[16], inv;
    chain_accumulate(n, head, rec, YPH, acc, &inv);

    const float4* rp = (const float4*)(R + (long)n * 16);
    float4* hp = (float4*)(H + (long)n * 16);
#pragma unroll
    for (int q = 0; q < 4; ++q) {
        float4 rr = rp[q];
        float4 o;
        float v;
        v = fmaf(acc[4 * q + 0], inv, rr.x); o.x = v > 0.0f ? v : expm1f(v);
        v = fmaf(acc[4 * q + 1], inv, rr.y); o.y = v > 0.0f ? v : expm1f(v);
        v = fmaf(acc[4 * q + 2], inv, rr.z); o.z = v > 0.0f ? v : expm1f(v);
        v = fmaf(acc[4 * q + 3], inv, rr.w); o.w = v > 0.0f ? v : expm1f(v);
        hp[q] = o;
    }
}

__global__ void aggregate_logsoftmax(const int* __restrict__ head,
                                     const int2* __restrict__ rec,
                                     const uint4* __restrict__ YPH,
                                     const float* __restrict__ R,
                                     float* __restrict__ out) {
    int n = blockIdx.x * blockDim.x + threadIdx.x;
    if (n >= N_NODES) return;
    float acc[16], inv;
    chain_accumulate(n, head, rec, YPH, acc, &inv);

    float v[16];
    const float4* rp = (const float4*)(R + (long)n * 16);
#pragma unroll
    for (int q = 0; q < 4; ++q) {
        float4 rr = rp[q];
        v[4 * q + 0] = fmaf(acc[4 * q + 0], inv, rr.x);
        v[4 * q + 1] = fmaf(acc[4 * q + 1], inv, rr.y);
        v[4 * q + 2] = fmaf(acc[4 * q + 2], inv, rr.z);
        v[4 * q + 3] = fmaf(acc[4 * q + 3], inv, rr.w);
    }
    float m = v[0];
#pragma unroll
    for (int i = 1; i < 16; ++i) m = fmaxf(m, v[i]);
    float s = 0.0f;
#pragma unroll
    for (int i = 0; i < 16; ++i) s += expf(v[i] - m);
    float lse = m + logf(s);

    float4* op = (float4*)(out + (long)n * 16);
#pragma unroll
    for (int q = 0; q < 4; ++q) {
        float4 o;
        o.x = v[4 * q + 0] - lse;
        o.y = v[4 * q + 1] - lse;
        o.z = v[4 * q + 2] - lse;
        o.w = v[4 * q + 3] - lse;
        op[q] = o;
    }
}

// ---------------------------------------------------------------------------
extern "C" void kernel_launch(void* const* d_in, const int* in_sizes, int n_in,
                              void* d_out, int out_size, void* d_ws, size_t ws_size,
                              hipStream_t stream) {
    const float* x         = (const float*)d_in[0];
    const float* edge_attr = (const float*)d_in[1];
    const int*   edge_idx  = (const int*)d_in[2];
    const float* W1        = (const float*)d_in[3];
    const float* root1     = (const float*)d_in[4];
    const float* b1        = (const float*)d_in[5];
    const float* W2        = (const float*)d_in[6];
    const float* root2     = (const float*)d_in[7];
    const float* b2        = (const float*)d_in[8];
    float* out = (float*)d_out;

    const int* src = edge_idx;
    const int* dst = edge_idx + N_EDGES;

    // workspace layout (16B-aligned base)
    char* ws = (char*)d_ws;
    int2*     rec  = (int2*)ws;                                  // E*8B  = 12.8 MB
    unsigned* YPH  = (unsigned*)(ws + (size_t)N_EDGES * 8);      // N*64B =  6.4 MB
    float*    R    = (float*)((char*)YPH + (size_t)N_NODES * 64);// N*64B =  6.4 MB
    float*    H    = R + (size_t)N_NODES * 16;                   // N*64B =  6.4 MB
    int*      head = (int*)(H + (size_t)N_NODES * 16);           // N*4B  =  0.4 MB

    dim3 gEdges((N_EDGES + 255) / 256);
    dim3 gNF((N_NODES * F + 255) / 256);
    dim3 gNodes64((N_NODES + 63) / 64);

    hipMemsetAsync(head, 0xFF, (size_t)N_NODES * 4, stream);  // head = -1
    build_links<<<gEdges, 256, 0, stream>>>(src, dst, edge_attr, head, rec);

    // ---- layer 1 ----
    node_transform<<<gNF, 256, 0, stream>>>(x, 48, W1, root1, b1, YPH, R, N_NODES);
    aggregate_elu<<<gNodes64, 64, 0, stream>>>(head, rec, (const uint4*)YPH, R, H);

    // ---- layer 2 ----
    node_transform<<<gNF, 256, 0, stream>>>(H, 16, W2, root2, b2, YPH, R, N_NODES);
    aggregate_logsoftmax<<<gNodes64, 64, 0, stream>>>(head, rec, (const uint4*)YPH, R, out);
}

// Round 6
// 265.515 us; speedup vs baseline: 1.7512x; 1.0873x over previous
//
#include <hip/hip_runtime.h>
#include <math.h>

#define N_NODES 100000
#define N_EDGES 1600000
#define F 16
#define KC 4   // interleaved chains per node

// ---------------------------------------------------------------------------
__device__ __forceinline__ unsigned bf16_rne(float x) {
    unsigned u = __float_as_uint(x);
    return (u + 0x7FFFu + ((u >> 16) & 1u)) >> 16;
}

// ---------------------------------------------------------------------------
// Transform body: one block of 256 threads covers 16 nodes x 16 features.
//   YPH[n*16+o] = bf16(X@W0) | bf16(X@(W1-W0))<<16
//   R[n*16+o]   = (X@root)[n,o] + bias[o]
__device__ __forceinline__ void transform_body(
        const float* __restrict__ X, int fin,
        const float* __restrict__ W, const float* __restrict__ root,
        const float* __restrict__ bias,
        unsigned* __restrict__ YPH, float* __restrict__ R,
        int bid, float* sW0, float* sWd, float* sR, float* sB) {
    int t = threadIdx.x;
    for (int i = t; i < fin * 16; i += 256) {
        float w0 = W[i];
        float w1 = W[fin * 16 + i];
        sW0[i] = w0;
        sWd[i] = w1 - w0;
        sR[i]  = root[i];
    }
    if (t < 16) sB[t] = bias[t];
    __syncthreads();

    int idx = bid * 256 + t;
    int n = idx >> 4;
    int o = idx & 15;
    if (n >= N_NODES) return;

    const float* xr = X + (long)n * fin;
    float a0 = 0.0f, a1 = 0.0f, ar = 0.0f;
    for (int f = 0; f < fin; ++f) {
        float xv = xr[f];
        a0 = fmaf(xv, sW0[f * 16 + o], a0);
        a1 = fmaf(xv, sWd[f * 16 + o], a1);
        ar = fmaf(xv, sR[f * 16 + o], ar);
    }
    YPH[idx] = bf16_rne(a0) | (bf16_rne(a1) << 16);
    R[idx]   = ar + sB[o];
}

// ---------------------------------------------------------------------------
// Build body: rec[e] = {next, src | u15<<17}; head[(dst<<2)|(e&3)] = e.
__device__ __forceinline__ void build_body(
        const int* __restrict__ src, const int* __restrict__ dst,
        const float* __restrict__ u, int* __restrict__ head,
        int2* __restrict__ rec, int bid) {
    int e = bid * 256 + threadIdx.x;
    if (e >= N_EDGES) return;
    int d = dst[e];
    int nx = atomicExch(&head[(d << 2) | (e & (KC - 1))], e);
    float uu = u[e];
    uu = uu < 0.0f ? 0.0f : (uu > 1.0f ? 1.0f : uu);
    int u15 = (int)fmaf(uu, 32767.0f, 0.5f);
    rec[e] = make_int2(nx, src[e] | (u15 << 17));
}

// Fused: even blocks run layer-1 transform (6250), odd blocks build (6250).
__global__ __launch_bounds__(256)
void fused_build_transform(const float* __restrict__ X,
                           const float* __restrict__ W,
                           const float* __restrict__ root,
                           const float* __restrict__ bias,
                           unsigned* __restrict__ YPH, float* __restrict__ R,
                           const int* __restrict__ src,
                           const int* __restrict__ dst,
                           const float* __restrict__ u,
                           int* __restrict__ head, int2* __restrict__ rec) {
    __shared__ float sW0[48 * 16];
    __shared__ float sWd[48 * 16];
    __shared__ float sR[48 * 16];
    __shared__ float sB[16];
    int bid = blockIdx.x >> 1;
    if ((blockIdx.x & 1) == 0)
        transform_body(X, 48, W, root, bias, YPH, R, bid, sW0, sWd, sR, sB);
    else
        build_body(src, dst, u, head, rec, bid);
}

// Standalone transform (layer 2, fin = 16)
__global__ __launch_bounds__(256)
void node_transform(const float* __restrict__ X, int fin,
                    const float* __restrict__ W,
                    const float* __restrict__ root,
                    const float* __restrict__ bias,
                    unsigned* __restrict__ YPH, float* __restrict__ R) {
    __shared__ float sW0[48 * 16];
    __shared__ float sWd[48 * 16];
    __shared__ float sR[48 * 16];
    __shared__ float sB[16];
    transform_body(X, fin, W, root, bias, YPH, R, blockIdx.x, sW0, sWd, sR, sB);
}

// ---------------------------------------------------------------------------
// 4 lanes per node (aligned quad); each lane walks one sub-chain, then a
// 2-round shuffle butterfly combines acc/deg. Lane h handles feature quad h.
__device__ __forceinline__ void chains_accumulate(
        int g, const int* __restrict__ head, const int2* __restrict__ rec,
        const uint4* __restrict__ YPH, float acc[16], float* inv_deg) {
#pragma unroll
    for (int i = 0; i < 16; ++i) acc[i] = 0.0f;
    int e = head[g];  // head[(n<<2)|h] == head[g]
    int deg = 0;
    while (e >= 0) {
        int2 r = rec[e];
        unsigned pk = (unsigned)r.y;
        float uu = (float)(pk >> 17) * (1.0f / 32767.0f);
        const uint4* yp = YPH + (size_t)(pk & 0x1FFFFu) * 4;
#pragma unroll
        for (int q = 0; q < 4; ++q) {
            uint4 w = yp[q];
            float y0, y1;
            y0 = __uint_as_float(w.x << 16);
            y1 = __uint_as_float(w.x & 0xFFFF0000u);
            acc[4 * q + 0] += fmaf(uu, y1, y0);
            y0 = __uint_as_float(w.y << 16);
            y1 = __uint_as_float(w.y & 0xFFFF0000u);
            acc[4 * q + 1] += fmaf(uu, y1, y0);
            y0 = __uint_as_float(w.z << 16);
            y1 = __uint_as_float(w.z & 0xFFFF0000u);
            acc[4 * q + 2] += fmaf(uu, y1, y0);
            y0 = __uint_as_float(w.w << 16);
            y1 = __uint_as_float(w.w & 0xFFFF0000u);
            acc[4 * q + 3] += fmaf(uu, y1, y0);
        }
        ++deg;
        e = r.x;
    }
    // butterfly combine across the 4 lanes of this node
#pragma unroll
    for (int mask = 1; mask <= 2; mask <<= 1) {
#pragma unroll
        for (int i = 0; i < 16; ++i) acc[i] += __shfl_xor(acc[i], mask);
        deg += __shfl_xor(deg, mask);
    }
    *inv_deg = 1.0f / (deg > 0 ? (float)deg : 1.0f);
}

__global__ __launch_bounds__(256)
void aggregate_elu(const int* __restrict__ head, const int2* __restrict__ rec,
                   const uint4* __restrict__ YPH, const float* __restrict__ R,
                   float* __restrict__ H) {
    int g = blockIdx.x * 256 + threadIdx.x;
    if (g >= N_NODES * KC) return;
    float acc[16], inv;
    chains_accumulate(g, head, rec, YPH, acc, &inv);
    int h = g & 3;
    // lane h handles feature quad h; addresses are g*16B -> fully coalesced
    float4 rr = *(const float4*)(R + (size_t)g * 4);
    float4 o;
    float v;
    v = fmaf(acc[4 * h + 0], inv, rr.x); o.x = v > 0.0f ? v : expm1f(v);
    v = fmaf(acc[4 * h + 1], inv, rr.y); o.y = v > 0.0f ? v : expm1f(v);
    v = fmaf(acc[4 * h + 2], inv, rr.z); o.z = v > 0.0f ? v : expm1f(v);
    v = fmaf(acc[4 * h + 3], inv, rr.w); o.w = v > 0.0f ? v : expm1f(v);
    *(float4*)(H + (size_t)g * 4) = o;
}

__global__ __launch_bounds__(256)
void aggregate_logsoftmax(const int* __restrict__ head,
                          const int2* __restrict__ rec,
                          const uint4* __restrict__ YPH,
                          const float* __restrict__ R,
                          float* __restrict__ out) {
    int g = blockIdx.x * 256 + threadIdx.x;
    if (g >= N_NODES * KC) return;
    float acc[16], inv;
    chains_accumulate(g, head, rec, YPH, acc, &inv);
    int h = g & 3;
    float4 rr = *(const float4*)(R + (size_t)g * 4);
    float vq[4];
    vq[0] = fmaf(acc[4 * h + 0], inv, rr.x);
    vq[1] = fmaf(acc[4 * h + 1], inv, rr.y);
    vq[2] = fmaf(acc[4 * h + 2], inv, rr.z);
    vq[3] = fmaf(acc[4 * h + 3], inv, rr.w);
    float m = fmaxf(fmaxf(vq[0], vq[1]), fmaxf(vq[2], vq[3]));
#pragma unroll
    for (int mask = 1; mask <= 2; mask <<= 1) m = fmaxf(m, __shfl_xor(m, mask));
    float s = expf(vq[0] - m) + expf(vq[1] - m) + expf(vq[2] - m) + expf(vq[3] - m);
#pragma unroll
    for (int mask = 1; mask <= 2; mask <<= 1) s += __shfl_xor(s, mask);
    float lse = m + logf(s);
    float4 o;
    o.x = vq[0] - lse;
    o.y = vq[1] - lse;
    o.z = vq[2] - lse;
    o.w = vq[3] - lse;
    *(float4*)(out + (size_t)g * 4) = o;
}

// ---------------------------------------------------------------------------
extern "C" void kernel_launch(void* const* d_in, const int* in_sizes, int n_in,
                              void* d_out, int out_size, void* d_ws, size_t ws_size,
                              hipStream_t stream) {
    const float* x         = (const float*)d_in[0];
    const float* edge_attr = (const float*)d_in[1];
    const int*   edge_idx  = (const int*)d_in[2];
    const float* W1        = (const float*)d_in[3];
    const float* root1     = (const float*)d_in[4];
    const float* b1        = (const float*)d_in[5];
    const float* W2        = (const float*)d_in[6];
    const float* root2     = (const float*)d_in[7];
    const float* b2        = (const float*)d_in[8];
    float* out = (float*)d_out;

    const int* src = edge_idx;
    const int* dst = edge_idx + N_EDGES;

    // workspace layout (16B-aligned base)
    char* ws = (char*)d_ws;
    int2*     rec  = (int2*)ws;                                   // 12.8 MB
    unsigned* YPH  = (unsigned*)(ws + (size_t)N_EDGES * 8);       //  6.4 MB
    float*    R    = (float*)((char*)YPH + (size_t)N_NODES * 64); //  6.4 MB
    float*    H    = R + (size_t)N_NODES * 16;                    //  6.4 MB
    int*      head = (int*)(H + (size_t)N_NODES * 16);            //  1.6 MB (N*KC)

    dim3 gNF((N_NODES * F + 255) / 256);          // 6250
    dim3 gFused(2 * 6250);                        // even: transform1, odd: build
    dim3 gAgg((N_NODES * KC + 255) / 256);        // 1563

    hipMemsetAsync(head, 0xFF, (size_t)N_NODES * KC * 4, stream);  // heads = -1
    fused_build_transform<<<gFused, 256, 0, stream>>>(
        x, W1, root1, b1, YPH, R, src, dst, edge_attr, head, rec);

    // ---- layer 1 aggregate ----
    aggregate_elu<<<gAgg, 256, 0, stream>>>(head, rec, (const uint4*)YPH, R, H);

    // ---- layer 2 ----
    node_transform<<<gNF, 256, 0, stream>>>(H, 16, W2, root2, b2, YPH, R);
    aggregate_logsoftmax<<<gAgg, 256, 0, stream>>>(head, rec, (const uint4*)YPH, R, out);
}

// Round 7
// 256.077 us; speedup vs baseline: 1.8157x; 1.0369x over previous
//
#include <hip/hip_runtime.h>
#include <math.h>

#define N_NODES 100000
#define N_EDGES 1600000
#define F 16
#define KC 8                      // interleaved chains per node
#define KSH 3

// ---------------------------------------------------------------------------
__device__ __forceinline__ unsigned bf16_rne(float x) {
    unsigned u = __float_as_uint(x);
    return (u + 0x7FFFu + ((u >> 16) & 1u)) >> 16;
}

// ---------------------------------------------------------------------------
// Transform body (layer 1): 256 threads = 16 nodes x 16 features.
//   YPH[n*16+o] = bf16(X@W0) | bf16(X@(W1-W0))<<16
//   R[n*16+o]   = (X@root)[n,o] + bias[o]
__device__ __forceinline__ void transform_body(
        const float* __restrict__ X, int fin,
        const float* __restrict__ W, const float* __restrict__ root,
        const float* __restrict__ bias,
        unsigned* __restrict__ YPH, float* __restrict__ R,
        int bid, float* sW0, float* sWd, float* sR, float* sB) {
    int t = threadIdx.x;
    for (int i = t; i < fin * 16; i += 256) {
        float w0 = W[i];
        float w1 = W[fin * 16 + i];
        sW0[i] = w0;
        sWd[i] = w1 - w0;
        sR[i]  = root[i];
    }
    if (t < 16) sB[t] = bias[t];
    __syncthreads();

    int idx = bid * 256 + t;
    int n = idx >> 4;
    int o = idx & 15;
    if (n >= N_NODES) return;

    const float* xr = X + (long)n * fin;
    float a0 = 0.0f, a1 = 0.0f, ar = 0.0f;
    for (int f = 0; f < fin; ++f) {
        float xv = xr[f];
        a0 = fmaf(xv, sW0[f * 16 + o], a0);
        a1 = fmaf(xv, sWd[f * 16 + o], a1);
        ar = fmaf(xv, sR[f * 16 + o], ar);
    }
    YPH[idx] = bf16_rne(a0) | (bf16_rne(a1) << 16);
    R[idx]   = ar + sB[o];
}

// ---------------------------------------------------------------------------
// Build body: rec[e] = {next, src | u15<<17}; head[(dst<<KSH)|(e&(KC-1))] = e.
__device__ __forceinline__ void build_body(
        const int* __restrict__ src, const int* __restrict__ dst,
        const float* __restrict__ u, int* __restrict__ head,
        int2* __restrict__ rec, int bid) {
    int e = bid * 256 + threadIdx.x;
    if (e >= N_EDGES) return;
    int d = dst[e];
    int nx = atomicExch(&head[(d << KSH) | (e & (KC - 1))], e);
    float uu = u[e];
    uu = uu < 0.0f ? 0.0f : (uu > 1.0f ? 1.0f : uu);
    int u15 = (int)fmaf(uu, 32767.0f, 0.5f);
    rec[e] = make_int2(nx, src[e] | (u15 << 17));
}

// Fused: even blocks transform layer 1 (6250), odd blocks build (6250).
__global__ __launch_bounds__(256)
void fused_build_transform(const float* __restrict__ X,
                           const float* __restrict__ W,
                           const float* __restrict__ root,
                           const float* __restrict__ bias,
                           unsigned* __restrict__ YPH, float* __restrict__ R,
                           const int* __restrict__ src,
                           const int* __restrict__ dst,
                           const float* __restrict__ u,
                           int* __restrict__ head, int2* __restrict__ rec) {
    __shared__ float sW0[48 * 16];
    __shared__ float sWd[48 * 16];
    __shared__ float sR[48 * 16];
    __shared__ float sB[16];
    int bid = blockIdx.x >> 1;
    if ((blockIdx.x & 1) == 0)
        transform_body(X, 48, W, root, bias, YPH, R, bid, sW0, sWd, sR, sB);
    else
        build_body(src, dst, u, head, rec, bid);
}

// ---------------------------------------------------------------------------
// KC lanes per node (aligned group); each lane walks one sub-chain, then a
// 3-round shuffle butterfly leaves FULL acc[16] + deg in every lane.
__device__ __forceinline__ void chains_accumulate(
        int g, const int* __restrict__ head, const int2* __restrict__ rec,
        const uint4* __restrict__ YPH, float acc[16], float* inv_deg) {
#pragma unroll
    for (int i = 0; i < 16; ++i) acc[i] = 0.0f;
    int e = head[g];
    int deg = 0;
    while (e >= 0) {
        int2 r = rec[e];
        unsigned pk = (unsigned)r.y;
        float uu = (float)(pk >> 17) * (1.0f / 32767.0f);
        const uint4* yp = YPH + (size_t)(pk & 0x1FFFFu) * 4;
#pragma unroll
        for (int q = 0; q < 4; ++q) {
            uint4 w = yp[q];
            float y0, y1;
            y0 = __uint_as_float(w.x << 16);
            y1 = __uint_as_float(w.x & 0xFFFF0000u);
            acc[4 * q + 0] += fmaf(uu, y1, y0);
            y0 = __uint_as_float(w.y << 16);
            y1 = __uint_as_float(w.y & 0xFFFF0000u);
            acc[4 * q + 1] += fmaf(uu, y1, y0);
            y0 = __uint_as_float(w.z << 16);
            y1 = __uint_as_float(w.z & 0xFFFF0000u);
            acc[4 * q + 2] += fmaf(uu, y1, y0);
            y0 = __uint_as_float(w.w << 16);
            y1 = __uint_as_float(w.w & 0xFFFF0000u);
            acc[4 * q + 3] += fmaf(uu, y1, y0);
        }
        ++deg;
        e = r.x;
    }
#pragma unroll
    for (int mask = 1; mask <= 4; mask <<= 1) {
#pragma unroll
        for (int i = 0; i < 16; ++i) acc[i] += __shfl_xor(acc[i], mask);
        deg += __shfl_xor(deg, mask);
    }
    *inv_deg = 1.0f / (deg > 0 ? (float)deg : 1.0f);
}

// ---------------------------------------------------------------------------
// Aggregate layer 1 + ELU + layer-2 transform fused in the epilogue.
// Each lane: full H row in registers -> 2 output features of H@{W0,Wd,root}.
__global__ __launch_bounds__(256)
void aggregate_elu_transform(const int* __restrict__ head,
                             const int2* __restrict__ rec,
                             const uint4* __restrict__ YPH1,
                             const float* __restrict__ R1,
                             const float* __restrict__ W2,
                             const float* __restrict__ root2,
                             const float* __restrict__ b2,
                             unsigned* __restrict__ YPH2,
                             float* __restrict__ R2) {
    __shared__ float sW0[16 * 16];
    __shared__ float sWd[16 * 16];
    __shared__ float sR[16 * 16];
    __shared__ float sB[16];
    int t = threadIdx.x;
    if (t < 256) {
        float w0 = W2[t];
        float w1 = W2[256 + t];
        sW0[t] = w0;
        sWd[t] = w1 - w0;
        sR[t]  = root2[t];
    }
    if (t < 16) sB[t] = b2[t];
    __syncthreads();

    int g = blockIdx.x * 256 + t;
    if (g >= N_NODES * KC) return;
    float acc[16], inv;
    chains_accumulate(g, head, rec, YPH1, acc, &inv);

    int n = g >> KSH;
    int h = g & (KC - 1);

    // full H row (ELU'd) in registers
    float h16[16];
    const float4* rp = (const float4*)(R1 + (size_t)n * 16);
#pragma unroll
    for (int q = 0; q < 4; ++q) {
        float4 rr = rp[q];
        float v;
        v = fmaf(acc[4 * q + 0], inv, rr.x); h16[4 * q + 0] = v > 0.0f ? v : expm1f(v);
        v = fmaf(acc[4 * q + 1], inv, rr.y); h16[4 * q + 1] = v > 0.0f ? v : expm1f(v);
        v = fmaf(acc[4 * q + 2], inv, rr.z); h16[4 * q + 2] = v > 0.0f ? v : expm1f(v);
        v = fmaf(acc[4 * q + 3], inv, rr.w); h16[4 * q + 3] = v > 0.0f ? v : expm1f(v);
    }

    // layer-2 transform: this lane's 2 output features o = 2h, 2h+1
    int o0 = 2 * h;
    float a0 = 0.0f, a1 = 0.0f, ar = 0.0f;   // feature o0
    float c0 = 0.0f, c1 = 0.0f, cr = 0.0f;   // feature o0+1
#pragma unroll
    for (int f = 0; f < 16; ++f) {
        float hv = h16[f];
        a0 = fmaf(hv, sW0[f * 16 + o0], a0);
        a1 = fmaf(hv, sWd[f * 16 + o0], a1);
        ar = fmaf(hv, sR[f * 16 + o0],  ar);
        c0 = fmaf(hv, sW0[f * 16 + o0 + 1], c0);
        c1 = fmaf(hv, sWd[f * 16 + o0 + 1], c1);
        cr = fmaf(hv, sR[f * 16 + o0 + 1],  cr);
    }
    // coalesced: index n*16 + 2h == 2g
    ((uint2*)YPH2)[g] = make_uint2(bf16_rne(a0) | (bf16_rne(a1) << 16),
                                   bf16_rne(c0) | (bf16_rne(c1) << 16));
    ((float2*)R2)[g] = make_float2(ar + sB[o0], cr + sB[o0 + 1]);
}

// ---------------------------------------------------------------------------
// Aggregate layer 2 + log-softmax. Each lane owns 2 features; butterfly for
// max/sum across the node's 8 lanes.
__global__ __launch_bounds__(256)
void aggregate_logsoftmax(const int* __restrict__ head,
                          const int2* __restrict__ rec,
                          const uint4* __restrict__ YPH,
                          const float* __restrict__ R,
                          float* __restrict__ out) {
    int g = blockIdx.x * 256 + threadIdx.x;
    if (g >= N_NODES * KC) return;
    float acc[16], inv;
    chains_accumulate(g, head, rec, YPH, acc, &inv);

    int h = g & (KC - 1);
    float2 rr = ((const float2*)R)[g];
    float v0 = fmaf(acc[2 * h + 0], inv, rr.x);
    float v1 = fmaf(acc[2 * h + 1], inv, rr.y);

    float m = fmaxf(v0, v1);
#pragma unroll
    for (int mask = 1; mask <= 4; mask <<= 1) m = fmaxf(m, __shfl_xor(m, mask));
    float s = expf(v0 - m) + expf(v1 - m);
#pragma unroll
    for (int mask = 1; mask <= 4; mask <<= 1) s += __shfl_xor(s, mask);
    float lse = m + logf(s);

    ((float2*)out)[g] = make_float2(v0 - lse, v1 - lse);
}

// ---------------------------------------------------------------------------
extern "C" void kernel_launch(void* const* d_in, const int* in_sizes, int n_in,
                              void* d_out, int out_size, void* d_ws, size_t ws_size,
                              hipStream_t stream) {
    const float* x         = (const float*)d_in[0];
    const float* edge_attr = (const float*)d_in[1];
    const int*   edge_idx  = (const int*)d_in[2];
    const float* W1        = (const float*)d_in[3];
    const float* root1     = (const float*)d_in[4];
    const float* b1        = (const float*)d_in[5];
    const float* W2        = (const float*)d_in[6];
    const float* root2     = (const float*)d_in[7];
    const float* b2        = (const float*)d_in[8];
    float* out = (float*)d_out;

    const int* src = edge_idx;
    const int* dst = edge_idx + N_EDGES;

    // workspace layout (16B-aligned base), total ~41.6 MB
    char* ws = (char*)d_ws;
    int2*     rec   = (int2*)ws;                                    // 12.8 MB
    unsigned* YPH1  = (unsigned*)(ws + (size_t)N_EDGES * 8);        //  6.4 MB
    unsigned* YPH2  = YPH1 + (size_t)N_NODES * 16;                  //  6.4 MB
    float*    R1    = (float*)(YPH2 + (size_t)N_NODES * 16);        //  6.4 MB
    float*    R2    = R1 + (size_t)N_NODES * 16;                    //  6.4 MB
    int*      head  = (int*)(R2 + (size_t)N_NODES * 16);            //  3.2 MB

    dim3 gFused(2 * 6250);
    dim3 gAgg((N_NODES * KC + 255) / 256);   // 3125

    hipMemsetAsync(head, 0xFF, (size_t)N_NODES * KC * 4, stream);
    fused_build_transform<<<gFused, 256, 0, stream>>>(
        x, W1, root1, b1, YPH1, R1, src, dst, edge_attr, head, rec);

    aggregate_elu_transform<<<gAgg, 256, 0, stream>>>(
        head, rec, (const uint4*)YPH1, R1, W2, root2, b2, YPH2, R2);

    aggregate_logsoftmax<<<gAgg, 256, 0, stream>>>(
        head, rec, (const uint4*)YPH2, R2, out);
}

// Round 8
// 234.936 us; speedup vs baseline: 1.9791x; 1.0900x over previous
//
#include <hip/hip_runtime.h>
#include <math.h>

#define N_NODES 100000
#define N_EDGES 1600000
#define KC 8                      // interleaved chains per node
#define KSH 3
#define CSR_CAP 24                // slots per node in CSR cache (4 B each)
#define CHAIN_BUF 15              // per-lane LDS buffer depth

// ---------------------------------------------------------------------------
__device__ __forceinline__ unsigned bf16_rne(float x) {
    unsigned u = __float_as_uint(x);
    return (u + 0x7FFFu + ((u >> 16) & 1u)) >> 16;
}

// accumulate one edge (pk = src | u15<<17) from packed-bf16 Y table
__device__ __forceinline__ void edge_accum(unsigned pk,
                                           const uint4* __restrict__ YPH,
                                           float acc[16]) {
    float uu = (float)(pk >> 17) * (1.0f / 32767.0f);
    const uint4* yp = YPH + (size_t)(pk & 0x1FFFFu) * 4;
#pragma unroll
    for (int q = 0; q < 4; ++q) {
        uint4 w = yp[q];
        acc[4 * q + 0] += fmaf(uu, __uint_as_float(w.x & 0xFFFF0000u),
                               __uint_as_float(w.x << 16));
        acc[4 * q + 1] += fmaf(uu, __uint_as_float(w.y & 0xFFFF0000u),
                               __uint_as_float(w.y << 16));
        acc[4 * q + 2] += fmaf(uu, __uint_as_float(w.z & 0xFFFF0000u),
                               __uint_as_float(w.z << 16));
        acc[4 * q + 3] += fmaf(uu, __uint_as_float(w.w & 0xFFFF0000u),
                               __uint_as_float(w.w << 16));
    }
}

// ---------------------------------------------------------------------------
// Transform body (layer 1): 256 threads = 16 nodes x 16 features.
__device__ __forceinline__ void transform_body(
        const float* __restrict__ X, int fin,
        const float* __restrict__ W, const float* __restrict__ root,
        const float* __restrict__ bias,
        unsigned* __restrict__ YPH, float* __restrict__ R,
        int bid, float* sW0, float* sWd, float* sR, float* sB) {
    int t = threadIdx.x;
    for (int i = t; i < fin * 16; i += 256) {
        float w0 = W[i];
        float w1 = W[fin * 16 + i];
        sW0[i] = w0;
        sWd[i] = w1 - w0;
        sR[i]  = root[i];
    }
    if (t < 16) sB[t] = bias[t];
    __syncthreads();

    int idx = bid * 256 + t;
    int n = idx >> 4;
    int o = idx & 15;
    if (n >= N_NODES) return;

    const float* xr = X + (long)n * fin;
    float a0 = 0.0f, a1 = 0.0f, ar = 0.0f;
    for (int f = 0; f < fin; ++f) {
        float xv = xr[f];
        a0 = fmaf(xv, sW0[f * 16 + o], a0);
        a1 = fmaf(xv, sWd[f * 16 + o], a1);
        ar = fmaf(xv, sR[f * 16 + o], ar);
    }
    YPH[idx] = bf16_rne(a0) | (bf16_rne(a1) << 16);
    R[idx]   = ar + sB[o];
}

// Build body: rec[e] = {next, src | u15<<17}; head[(dst<<KSH)|(e&(KC-1))] = e.
__device__ __forceinline__ void build_body(
        const int* __restrict__ src, const int* __restrict__ dst,
        const float* __restrict__ u, int* __restrict__ head,
        int2* __restrict__ rec, int bid) {
    int e = bid * 256 + threadIdx.x;
    if (e >= N_EDGES) return;
    int d = dst[e];
    int nx = atomicExch(&head[(d << KSH) | (e & (KC - 1))], e);
    float uu = u[e];
    uu = uu < 0.0f ? 0.0f : (uu > 1.0f ? 1.0f : uu);
    int u15 = (int)fmaf(uu, 32767.0f, 0.5f);
    rec[e] = make_int2(nx, src[e] | (u15 << 17));
}

// Fused: even blocks transform layer 1 (6250), odd blocks build (6250).
__global__ __launch_bounds__(256)
void fused_build_transform(const float* __restrict__ X,
                           const float* __restrict__ W,
                           const float* __restrict__ root,
                           const float* __restrict__ bias,
                           unsigned* __restrict__ YPH, float* __restrict__ R,
                           const int* __restrict__ src,
                           const int* __restrict__ dst,
                           const float* __restrict__ u,
                           int* __restrict__ head, int2* __restrict__ rec) {
    __shared__ float sW0[48 * 16];
    __shared__ float sWd[48 * 16];
    __shared__ float sR[48 * 16];
    __shared__ float sB[16];
    int bid = blockIdx.x >> 1;
    if ((blockIdx.x & 1) == 0)
        transform_body(X, 48, W, root, bias, YPH, R, bid, sW0, sWd, sR, sB);
    else
        build_body(src, dst, u, head, rec, bid);
}

// ---------------------------------------------------------------------------
// Aggregate layer 1 + ELU + layer-2 transform, and EMIT per-node CSR cache.
// grid is exact (800000 = 3125*256): all lanes active, shuffles safe.
__global__ __launch_bounds__(256)
void aggregate_elu_transform(const int* __restrict__ head,
                             const int2* __restrict__ rec,
                             const uint4* __restrict__ YPH1,
                             const float* __restrict__ R1,
                             const float* __restrict__ W2,
                             const float* __restrict__ root2,
                             const float* __restrict__ b2,
                             unsigned* __restrict__ YPH2,
                             float* __restrict__ R2,
                             unsigned* __restrict__ csr,
                             unsigned char* __restrict__ deg,
                             int use_csr) {
    __shared__ float sW0[16 * 16];
    __shared__ float sWd[16 * 16];
    __shared__ float sR[16 * 16];
    __shared__ float sB[16];
    __shared__ unsigned sbuf[256 * CHAIN_BUF];   // per-lane edge buffer
    int t = threadIdx.x;
    {
        float w0 = W2[t];
        float w1 = W2[256 + t];
        sW0[t] = w0;
        sWd[t] = w1 - w0;
        sR[t]  = root2[t];
    }
    if (t < 16) sB[t] = b2[t];
    __syncthreads();

    int g = blockIdx.x * 256 + t;
    int n = g >> KSH;
    int h = g & (KC - 1);

    float acc[16];
#pragma unroll
    for (int i = 0; i < 16; ++i) acc[i] = 0.0f;

    unsigned* mybuf = sbuf + t * CHAIN_BUF;
    int e = head[g];
    int cnt = 0;
    while (e >= 0) {
        int2 r = rec[e];
        unsigned pk = (unsigned)r.y;
        if (cnt < CHAIN_BUF) mybuf[cnt] = pk;
        ++cnt;
        edge_accum(pk, YPH1, acc);
        e = r.x;
    }

    // octet totals / prefix (lanes of a node are an aligned group of 8)
    int base = (t & 63) & ~7;
    int tot = 0, mx = 0, pre = 0;
#pragma unroll
    for (int k = 0; k < 8; ++k) {
        int ck = __shfl(cnt, base + k, 64);
        tot += ck;
        mx = ck > mx ? ck : mx;
        if (k < h) pre += ck;
    }

    if (use_csr) {
        bool spill = (tot > CSR_CAP) || (mx > CHAIN_BUF);
        if (!spill) {
            unsigned* dp = csr + (size_t)n * CSR_CAP + pre;
            for (int i = 0; i < cnt; ++i) dp[i] = mybuf[i];
        }
        if (h == 0) deg[n] = spill ? (unsigned char)255 : (unsigned char)tot;
    }

    // butterfly: full acc[16] in every lane of the octet
#pragma unroll
    for (int mask = 1; mask <= 4; mask <<= 1) {
#pragma unroll
        for (int i = 0; i < 16; ++i) acc[i] += __shfl_xor(acc[i], mask);
    }
    float inv = 1.0f / (tot > 0 ? (float)tot : 1.0f);

    // full H row (ELU'd) in registers
    float h16[16];
    const float4* rp = (const float4*)(R1 + (size_t)n * 16);
#pragma unroll
    for (int q = 0; q < 4; ++q) {
        float4 rr = rp[q];
        float v;
        v = fmaf(acc[4 * q + 0], inv, rr.x); h16[4 * q + 0] = v > 0.0f ? v : expm1f(v);
        v = fmaf(acc[4 * q + 1], inv, rr.y); h16[4 * q + 1] = v > 0.0f ? v : expm1f(v);
        v = fmaf(acc[4 * q + 2], inv, rr.z); h16[4 * q + 2] = v > 0.0f ? v : expm1f(v);
        v = fmaf(acc[4 * q + 3], inv, rr.w); h16[4 * q + 3] = v > 0.0f ? v : expm1f(v);
    }

    // layer-2 transform: this lane's 2 output features o = 2h, 2h+1
    int o0 = 2 * h;
    float a0 = 0.0f, a1 = 0.0f, ar = 0.0f;
    float c0 = 0.0f, c1 = 0.0f, cr = 0.0f;
#pragma unroll
    for (int f = 0; f < 16; ++f) {
        float hv = h16[f];
        a0 = fmaf(hv, sW0[f * 16 + o0], a0);
        a1 = fmaf(hv, sWd[f * 16 + o0], a1);
        ar = fmaf(hv, sR[f * 16 + o0],  ar);
        c0 = fmaf(hv, sW0[f * 16 + o0 + 1], c0);
        c1 = fmaf(hv, sWd[f * 16 + o0 + 1], c1);
        cr = fmaf(hv, sR[f * 16 + o0 + 1],  cr);
    }
    ((uint2*)YPH2)[g] = make_uint2(bf16_rne(a0) | (bf16_rne(a1) << 16),
                                   bf16_rne(c0) | (bf16_rne(c1) << 16));
    ((float2*)R2)[g] = make_float2(ar + sB[o0], cr + sB[o0 + 1]);
}

// ---------------------------------------------------------------------------
// Aggregate layer 2 + log-softmax. CSR fast path; chain-walk fallback for
// spilled nodes (deg==255) or when CSR disabled.
__global__ __launch_bounds__(256)
void aggregate_logsoftmax(const int* __restrict__ head,
                          const int2* __restrict__ rec,
                          const uint4* __restrict__ YPH,
                          const float* __restrict__ R,
                          float* __restrict__ out,
                          const unsigned* __restrict__ csr,
                          const unsigned char* __restrict__ deg,
                          int use_csr) {
    int g = blockIdx.x * 256 + threadIdx.x;
    int n = g >> KSH;
    int h = g & (KC - 1);

    float acc[16];
#pragma unroll
    for (int i = 0; i < 16; ++i) acc[i] = 0.0f;
    int cnt = 0;

    int d = use_csr ? (int)deg[n] : 255;
    if (d != 255) {
        const unsigned* sp = csr + (size_t)n * CSR_CAP;
        for (int j = h; j < d; j += KC) {
            edge_accum(sp[j], YPH, acc);
            ++cnt;
        }
    } else {
        int e = head[g];
        while (e >= 0) {
            int2 r = rec[e];
            edge_accum((unsigned)r.y, YPH, acc);
            ++cnt;
            e = r.x;
        }
    }

#pragma unroll
    for (int mask = 1; mask <= 4; mask <<= 1) {
#pragma unroll
        for (int i = 0; i < 16; ++i) acc[i] += __shfl_xor(acc[i], mask);
        cnt += __shfl_xor(cnt, mask);
    }
    float inv = 1.0f / (cnt > 0 ? (float)cnt : 1.0f);

    float2 rr = ((const float2*)R)[g];
    float v0 = fmaf(acc[2 * h + 0], inv, rr.x);
    float v1 = fmaf(acc[2 * h + 1], inv, rr.y);

    float m = fmaxf(v0, v1);
#pragma unroll
    for (int mask = 1; mask <= 4; mask <<= 1) m = fmaxf(m, __shfl_xor(m, mask));
    float s = expf(v0 - m) + expf(v1 - m);
#pragma unroll
    for (int mask = 1; mask <= 4; mask <<= 1) s += __shfl_xor(s, mask);
    float lse = m + logf(s);

    ((float2*)out)[g] = make_float2(v0 - lse, v1 - lse);
}

// ---------------------------------------------------------------------------
extern "C" void kernel_launch(void* const* d_in, const int* in_sizes, int n_in,
                              void* d_out, int out_size, void* d_ws, size_t ws_size,
                              hipStream_t stream) {
    const float* x         = (const float*)d_in[0];
    const float* edge_attr = (const float*)d_in[1];
    const int*   edge_idx  = (const int*)d_in[2];
    const float* W1        = (const float*)d_in[3];
    const float* root1     = (const float*)d_in[4];
    const float* b1        = (const float*)d_in[5];
    const float* W2        = (const float*)d_in[6];
    const float* root2     = (const float*)d_in[7];
    const float* b2        = (const float*)d_in[8];
    float* out = (float*)d_out;

    const int* src = edge_idx;
    const int* dst = edge_idx + N_EDGES;

    // workspace layout (byte offsets, all 16B-aligned)
    char* ws = (char*)d_ws;
    int2*          rec  = (int2*)(ws);                         // 12,800,000
    unsigned*      YPH1 = (unsigned*)(ws + 12800000);          //  6,400,000
    unsigned*      YPH2 = (unsigned*)(ws + 19200000);          //  6,400,000
    float*         R1   = (float*)(ws + 25600000);             //  6,400,000
    float*         R2   = (float*)(ws + 32000000);             //  6,400,000
    int*           head = (int*)(ws + 38400000);               //  3,200,000
    unsigned*      csr  = (unsigned*)(ws + 41600000);          //  9,600,000
    unsigned char* deg  = (unsigned char*)(ws + 51200000);     //    100,000
    const size_t need_csr = 51300000;
    int use_csr = (ws_size >= need_csr) ? 1 : 0;

    dim3 gFused(2 * 6250);
    dim3 gAgg((N_NODES * KC) / 256);   // 3125 exact

    hipMemsetAsync(head, 0xFF, (size_t)N_NODES * KC * 4, stream);
    fused_build_transform<<<gFused, 256, 0, stream>>>(
        x, W1, root1, b1, YPH1, R1, src, dst, edge_attr, head, rec);

    aggregate_elu_transform<<<gAgg, 256, 0, stream>>>(
        head, rec, (const uint4*)YPH1, R1, W2, root2, b2, YPH2, R2,
        csr, deg, use_csr);

    aggregate_logsoftmax<<<gAgg, 256, 0, stream>>>(
        head, rec, (const uint4*)YPH2, R2, out, csr, deg, use_csr);
}